// Round 1
// baseline (2126.942 us; speedup 1.0000x reference)
//
#include <hip/hip_runtime.h>

#define TPB 256
#define D 128

// One fused kernel template:
//   y_row = (SCALE_IN ? Xin[row]/cnt_in[row] : Xin[row]) @ W^T + bias
//   if RELU: y = max(y,0)
//   if SCATTER: atomicAdd into Out[idx[row]] (+ cnt_out histogram)
//   else: Out[row] = y   (safe in-place: waves own disjoint rows)
//
// Layout: 256 threads = 4 waves; wave owns 16 rows of a 64-row tile; lane owns
// cols {lane, lane+64}. W staged k-major in LDS (64 KB -> 2 blocks/CU); X rows
// are wave-uniform => scalar loads feed v_fmac via SGPR operand.
template<bool RELU, bool SCATTER, bool SCALE_IN>
__global__ __launch_bounds__(TPB, 2)
void fused_lin(const float* __restrict__ Xin,
               const float* __restrict__ W,
               const float* __restrict__ bias,
               const float* __restrict__ cnt_in,
               const int*   __restrict__ idx,
               float* __restrict__ Out,
               float* __restrict__ cnt_out,
               int nrows, int ntiles)
{
    __shared__ float Wt[D * D];  // Wt[k*D + c] = W[c*D + k]
    const int t    = threadIdx.x;
    const int lane = t & 63;
    const int wid  = __builtin_amdgcn_readfirstlane(t >> 6);

    // Stage W transposed (coalesced float4 global reads; LDS store conflicts
    // amortized by the grid-stride tile loop).
    #pragma unroll
    for (int u = 0; u < 16; ++u) {
        int flat = u * 1024 + t * 4;          // covers 16384 floats
        int c = flat >> 7, k = flat & 127;
        float4 wv = *(const float4*)(W + flat);
        Wt[(k + 0) * D + c] = wv.x;
        Wt[(k + 1) * D + c] = wv.y;
        Wt[(k + 2) * D + c] = wv.z;
        Wt[(k + 3) * D + c] = wv.w;
    }
    const float b0 = bias[lane];
    const float b1 = bias[lane + 64];
    __syncthreads();

    for (int tile = blockIdx.x; tile < ntiles; tile += gridDim.x) {
        const int r0 = tile * 64 + wid * 16;   // this wave's 16 rows
        if (r0 >= nrows) continue;             // no barriers inside loop: safe

        float acc0[16], acc1[16];
        #pragma unroll
        for (int r = 0; r < 16; ++r) { acc0[r] = 0.f; acc1[r] = 0.f; }

        if (r0 + 16 <= nrows) {
            // fast path: wave-uniform base + compile-time offsets -> s_load
            const float* xb = Xin + (size_t)r0 * D;
            #pragma unroll 4
            for (int k = 0; k < D; ++k) {
                float w0 = Wt[k * D + lane];
                float w1 = Wt[k * D + lane + 64];
                #pragma unroll
                for (int r = 0; r < 16; ++r) {
                    float x = xb[r * D + k];
                    acc0[r] += x * w0;
                    acc1[r] += x * w1;
                }
            }
        } else {
            // tail tile: clamp row reads (harmless dup), guard writes below
            #pragma unroll 2
            for (int k = 0; k < D; ++k) {
                float w0 = Wt[k * D + lane];
                float w1 = Wt[k * D + lane + 64];
                #pragma unroll
                for (int r = 0; r < 16; ++r) {
                    int rr = (r0 + r < nrows) ? (r0 + r) : (nrows - 1);
                    float x = Xin[(size_t)rr * D + k];
                    acc0[r] += x * w0;
                    acc1[r] += x * w1;
                }
            }
        }

        #pragma unroll
        for (int r = 0; r < 16; ++r) {
            int row = r0 + r;
            if (row >= nrows) break;
            float y0 = acc0[r], y1 = acc1[r];
            float bb0 = b0, bb1 = b1;
            if (SCALE_IN) {
                float c = cnt_in[row];
                float s = (c > 0.f) ? (1.f / c) : 0.f;
                y0 *= s; y1 *= s;
                if (c <= 0.f) { bb0 = 0.f; bb1 = 0.f; }  // empty segment -> 0
            }
            y0 += bb0; y1 += bb1;
            if (RELU) { y0 = fmaxf(y0, 0.f); y1 = fmaxf(y1, 0.f); }
            if (SCATTER) {
                int seg = idx[row];
                float* o = Out + (size_t)seg * D;
                unsafeAtomicAdd(o + lane, y0);
                unsafeAtomicAdd(o + lane + 64, y1);
                if (lane == 0) unsafeAtomicAdd(cnt_out + seg, 1.0f);
            } else {
                float* o = Out + (size_t)row * D;
                o[lane]      = y0;
                o[lane + 64] = y1;
            }
        }
    }
}

extern "C" void kernel_launch(void* const* d_in, const int* in_sizes, int n_in,
                              void* d_out, int out_size, void* d_ws, size_t ws_size,
                              hipStream_t stream) {
    const float* x_building = (const float*)d_in[0];   // 1048576 x 128
    const int*   assign_bc  = (const int*)  d_in[1];   // 1048576
    const int*   assign_ct  = (const int*)  d_in[2];   // 50000
    const float* w1 = (const float*)d_in[3];
    const float* b1 = (const float*)d_in[4];
    const float* w2 = (const float*)d_in[5];
    const float* b2 = (const float*)d_in[6];
    const float* w3 = (const float*)d_in[7];
    const float* b3 = (const float*)d_in[8];
    const float* w4 = (const float*)d_in[9];
    const float* b4 = (const float*)d_in[10];

    const int N_BUILD = 1048576;
    const int N_CABLE = 50000;
    const int N_TRANS = 2000;

    float* out        = (float*)d_out;
    float* S_c        = out;                       // 50000 x 128 (x_cable slot)
    float* S_t        = out + (size_t)N_CABLE * D; // 2000 x 128 (x_trans slot)
    float* cnt_c      = (float*)d_ws;              // 50000
    float* cnt_t      = cnt_c + N_CABLE;           // 2000

    // zero accumulators (harness poisons d_out/d_ws with 0xAA)
    hipMemsetAsync(d_out, 0, (size_t)out_size * sizeof(float), stream);
    hipMemsetAsync(d_ws, 0, (size_t)(N_CABLE + N_TRANS) * sizeof(float), stream);

    // K1: h1 = relu(X@W1^T+b1) scatter-sum into S_c (+cnt_c)
    {
        int ntiles = N_BUILD / 64;  // 16384, exact
        fused_lin<true, true, false><<<512, TPB, 0, stream>>>(
            x_building, w1, b1, nullptr, assign_bc, S_c, cnt_c, N_BUILD, ntiles);
    }
    // K2: x_cable = (S_c/cnt)@W2^T + b2, in place
    {
        int ntiles = (N_CABLE + 63) / 64;  // 782
        fused_lin<false, false, true><<<512, TPB, 0, stream>>>(
            S_c, w2, b2, cnt_c, nullptr, S_c, nullptr, N_CABLE, ntiles);
    }
    // K3: h2 = relu(x_cable@W3^T+b3) scatter-sum into S_t (+cnt_t)
    {
        int ntiles = (N_CABLE + 63) / 64;
        fused_lin<true, true, false><<<512, TPB, 0, stream>>>(
            S_c, w3, b3, nullptr, assign_ct, S_t, cnt_t, N_CABLE, ntiles);
    }
    // K4: x_trans = (S_t/cnt)@W4^T + b4, in place
    {
        int ntiles = (N_TRANS + 63) / 64;  // 32
        fused_lin<false, false, true><<<32, TPB, 0, stream>>>(
            S_t, w4, b4, cnt_t, nullptr, S_t, nullptr, N_TRANS, ntiles);
    }
}